// Round 1
// baseline (3860.404 us; speedup 1.0000x reference)
//
#include <hip/hip_runtime.h>

// VoiceModel: 2 branches x { scalar-LSTM(1->1,L2) over T=512 per (b,class),
// then LSTM(1->256,L2) over 128 class-steps }, concat -> MLP(512->200->128).
// Phase 2 uses f16 MFMA (16x16x16) with register-resident recurrent weights,
// batch-partitioned (no inter-block comm), h carried in an LDS fragment image.

typedef _Float16 f16;
typedef __attribute__((ext_vector_type(4))) _Float16 f16x4;
typedef __attribute__((ext_vector_type(4))) float f32x4;

#define NBATCH 256
#define NTIME  512
#define NCLS   128
#define NHID   256

__device__ __forceinline__ float sigf(float x) {
    return __builtin_amdgcn_rcpf(1.0f + __expf(-x));
}
__device__ __forceinline__ float tanh_f(float x) {
    return fmaf(2.0f, __builtin_amdgcn_rcpf(1.0f + __expf(-2.0f * x)), -1.0f);
}

// ---------------- K0: convert 6 weight matrices (1024x256 f32) to f16 --------
struct P6 {
    const float* s0; const float* s1; const float* s2;
    const float* s3; const float* s4; const float* s5;
};

__global__ __launch_bounds__(256) void k_cvt(P6 p, f16* __restrict__ dst) {
    int i = blockIdx.x * 256 + threadIdx.x;      // 6 * 262144 total
    int seg = i >> 18, off = i & 262143;
    const float* s = seg == 0 ? p.s0 : seg == 1 ? p.s1 : seg == 2 ? p.s2
                   : seg == 3 ? p.s3 : seg == 4 ? p.s4 : p.s5;
    dst[i] = (f16)s[off];
}

// ---------------- K1: scalar 2-layer LSTM per (branch, b, class) -------------
__global__ __launch_bounds__(128) void k_scalar_lstm(
    const int* __restrict__ ln, const int* __restrict__ rn,
    const float* __restrict__ tlW, const float* __restrict__ tlU, const float* __restrict__ tlb,
    const float* __restrict__ trW, const float* __restrict__ trU, const float* __restrict__ trb,
    float* __restrict__ states)
{
    __shared__ int tok[NTIME];
    const int bid = blockIdx.x;
    const int branch = bid >> 8;
    const int b = bid & 255;
    const int* tp = (branch ? rn : ln) + (size_t)b * (4 * NTIME);  // voice 0
    for (int i = threadIdx.x; i < NTIME; i += 128) tok[i] = tp[i];
    __syncthreads();
    const float* W  = branch ? trW : tlW;   // Wih
    const float* U  = branch ? trU : tlU;   // Whh
    const float* Bb = branch ? trb : tlb;
    const float u00 = U[0], u01 = U[1], u02 = U[2], u03 = U[3];
    const float f00 = Bb[0], f01 = Bb[1], f02 = Bb[2], f03 = Bb[3];
    const float o00 = f00 + W[0], o01 = f01 + W[1], o02 = f02 + W[2], o03 = f03 + W[3];
    const float w10 = W[4], w11 = W[5], w12 = W[6], w13 = W[7];
    const float u10 = U[4], u11 = U[5], u12 = U[6], u13 = U[7];
    const float b10 = Bb[4], b11 = Bb[5], b12 = Bb[6], b13 = Bb[7];
    const int n = threadIdx.x;
    float h0 = 0.f, c0 = 0.f, h1 = 0.f, c1 = 0.f;
    for (int t = 0; t < NTIME; ++t) {
        const bool x = (tok[t] == n);
        float pi = fmaf(u00, h0, x ? o00 : f00);
        float pf = fmaf(u01, h0, x ? o01 : f01);
        float pg = fmaf(u02, h0, x ? o02 : f02);
        float po = fmaf(u03, h0, x ? o03 : f03);
        float ig = sigf(pi), fg = sigf(pf), gg = tanh_f(pg), og = sigf(po);
        c0 = fmaf(fg, c0, ig * gg);
        h0 = og * tanh_f(c0);
        pi = fmaf(w10, h0, fmaf(u10, h1, b10));
        pf = fmaf(w11, h0, fmaf(u11, h1, b11));
        pg = fmaf(w12, h0, fmaf(u12, h1, b12));
        po = fmaf(w13, h0, fmaf(u13, h1, b13));
        ig = sigf(pi); fg = sigf(pf); gg = tanh_f(pg); og = sigf(po);
        c1 = fmaf(fg, c1, ig * gg);
        h1 = og * tanh_f(c1);
    }
    states[((size_t)(branch * NBATCH + b)) * NCLS + n] = h1;
}

// ---------------- K2/K3: big LSTM recurrence, one layer per kernel -----------
// Grid: 32 blocks = 2 branches x 16 batch-tiles (M=16). Block: 1024 thr = 16 waves.
// Wave w owns hidden rows [w*16, w*16+16) for all 4 gates; Whh fragments are
// register-resident: wreg[g][kt] holds Whh[g*256 + w*16 + fr][kt*16 + fq*4 .. +3].
// h lives in LDS as a 16x16x16f16 A-fragment image: elem (m,k) at
// lds_h[(k>>4)*256 + (m + 16*((k&15)>>2))*4 + (k&3)].
template <int IS_B1>
__global__ __launch_bounds__(1024) void k_rec(
    const float* __restrict__ states,      // B0: scalar-lstm outputs
    const f16* __restrict__ wrec,          // resident recurrent weights (2 branches)
    const f16* __restrict__ wih1,          // B1: streamed input weights
    const f16* __restrict__ h0img,         // B1: H0 fragment images
    f16* __restrict__ h0out,               // B0: H0 fragment images out
    const float* __restrict__ wih0L, const float* __restrict__ wih0R,  // B0
    const float* __restrict__ bL, const float* __restrict__ bR,
    float* __restrict__ h1out)             // B1: final top hidden (2,256,256) f32
{
    __shared__ f16 lds_h[16 * 256];        // 8 KB fragment image of h (16 x 256)
    __shared__ float lds_st[16 * NCLS];    // 8 KB, B0 only
    const int bid = blockIdx.x;
    const int branch = bid >> 4, bblk = bid & 15;
    const int tid = threadIdx.x;
    const int w = tid >> 6, l = tid & 63, fr = l & 15, fq = l >> 4;

    // resident recurrent weight fragments (128 VGPRs/lane)
    f16x4 wreg[4][16];
    {
        const f16* wbase = wrec + ((size_t)branch << 18);
#pragma unroll
        for (int g = 0; g < 4; ++g) {
            const int n = g * 256 + w * 16 + fr;
#pragma unroll
            for (int kt = 0; kt < 16; ++kt)
                wreg[g][kt] = *(const f16x4*)(wbase + n * 256 + kt * 16 + fq * 4);
        }
    }
    const float* bias = branch ? bR : bL;
    float bv[4], w0v[4];
#pragma unroll
    for (int g = 0; g < 4; ++g) {
        const int n = g * 256 + w * 16 + fr;
        bv[g] = bias[n];
        if (!IS_B1) w0v[g] = (branch ? wih0R : wih0L)[n];
    }
    ((uint2*)lds_h)[tid] = (uint2){0u, 0u};            // h = 0
    if (!IS_B1) {
        for (int i = tid; i < 16 * NCLS; i += 1024)
            lds_st[i] = states[((size_t)(branch * NBATCH + bblk * 16 + (i >> 7))) * NCLS + (i & 127)];
    }
    float c[4] = {0.f, 0.f, 0.f, 0.f};
    __syncthreads();

    for (int t = 0; t < NCLS; ++t) {
        f16x4 af[16];
#pragma unroll
        for (int kt = 0; kt < 16; ++kt)
            af[kt] = *(const f16x4*)(lds_h + kt * 256 + l * 4);
        f32x4 acc[4];
#pragma unroll
        for (int g = 0; g < 4; ++g) { f32x4 z = {0.f, 0.f, 0.f, 0.f}; acc[g] = z; }

        if (IS_B1) {
            // input contribution: h0[t] @ Wih1^T  (h0 frags from global, Wih1 streamed from L2)
            const f16* img = h0img + ((size_t)((branch * 16 + bblk) * NCLS + t)) * 4096;
            const f16* wi = wih1 + ((size_t)branch << 18);
#pragma unroll
            for (int kt = 0; kt < 16; ++kt) {
                const f16x4 a0 = *(const f16x4*)(img + kt * 256 + l * 4);
#pragma unroll
                for (int g = 0; g < 4; ++g) {
                    const f16x4 wf = *(const f16x4*)(wi + (g * 256 + w * 16 + fr) * 256 + kt * 16 + fq * 4);
                    acc[g] = __builtin_amdgcn_mfma_f32_16x16x16f16(a0, wf, acc[g], 0, 0, 0);
                }
            }
        }
#pragma unroll
        for (int kt = 0; kt < 16; ++kt)
#pragma unroll
            for (int g = 0; g < 4; ++g)
                acc[g] = __builtin_amdgcn_mfma_f32_16x16x16f16(af[kt], wreg[g][kt], acc[g], 0, 0, 0);

        // gates, fully in-register: lane holds pre[m=4*fq+r][n=g*256+w*16+fr]
        float st[4];
        if (!IS_B1) {
#pragma unroll
            for (int r = 0; r < 4; ++r) st[r] = lds_st[(fq * 4 + r) * NCLS + t];
        }
        float hn[4];
#pragma unroll
        for (int r = 0; r < 4; ++r) {
            float pi = acc[0][r] + bv[0];
            float pf = acc[1][r] + bv[1];
            float pg = acc[2][r] + bv[2];
            float po = acc[3][r] + bv[3];
            if (!IS_B1) {
                pi = fmaf(st[r], w0v[0], pi);
                pf = fmaf(st[r], w0v[1], pf);
                pg = fmaf(st[r], w0v[2], pg);
                po = fmaf(st[r], w0v[3], po);
            }
            const float ig = sigf(pi), fg = sigf(pf), gg = tanh_f(pg), og = sigf(po);
            c[r] = fmaf(fg, c[r], ig * gg);
            hn[r] = og * tanh_f(c[r]);
        }
        __syncthreads();                    // all frag reads of h(t-1) done
#pragma unroll
        for (int r = 0; r < 4; ++r) {
            const int m = fq * 4 + r;
            const int hh = w * 16 + fr;     // k index
            lds_h[(hh >> 4) * 256 + (m + 16 * ((hh & 15) >> 2)) * 4 + (hh & 3)] = (f16)hn[r];
        }
        __syncthreads();                    // h(t) image complete
        if (!IS_B1) {
            f16* dst = h0out + ((size_t)((branch * 16 + bblk) * NCLS + t)) * 4096;
            ((uint2*)dst)[tid] = ((const uint2*)lds_h)[tid];
        } else if (t == NCLS - 1) {
#pragma unroll
            for (int r = 0; r < 4; ++r) {
                const int m = bblk * 16 + fq * 4 + r;
                h1out[((size_t)(branch * NBATCH + m)) * NHID + w * 16 + fr] = hn[r];
            }
        }
    }
}

// ---------------- K4: MLP head (2H -> 200 -> 128), f32 ------------------------
__global__ __launch_bounds__(256) void k_mlp(
    const float* __restrict__ h1all,   // [2][256][256]
    const float* __restrict__ W1, const float* __restrict__ b1,
    const float* __restrict__ W2, const float* __restrict__ b2,
    float* __restrict__ out)
{
    __shared__ float hrow[512];
    __shared__ float hid[200];
    const int b = blockIdx.x, tid = threadIdx.x;
    hrow[tid]       = h1all[(size_t)b * NHID + tid];
    hrow[256 + tid] = h1all[(size_t)(NBATCH + b) * NHID + tid];
    __syncthreads();
    if (tid < 200) {
        float a = b1[tid];
        const float* wr = W1 + (size_t)tid * 512;
        for (int k = 0; k < 512; ++k) a = fmaf(wr[k], hrow[k], a);
        hid[tid] = fmaxf(a, 0.f);
    }
    __syncthreads();
    if (tid < 128) {
        float a = b2[tid];
        const float* wr = W2 + (size_t)tid * 200;
        for (int j = 0; j < 200; ++j) a = fmaf(wr[j], hid[j], a);
        out[(size_t)b * 128 + tid] = a;
    }
}

// ---------------- launch ------------------------------------------------------
extern "C" void kernel_launch(void* const* d_in, const int* in_sizes, int n_in,
                              void* d_out, int out_size, void* d_ws, size_t ws_size,
                              hipStream_t stream)
{
    (void)in_sizes; (void)n_in; (void)out_size; (void)ws_size;
    const int*   ln    = (const int*)d_in[0];
    const int*   rn    = (const int*)d_in[2];
    const float* tlW   = (const float*)d_in[4];
    const float* tlU   = (const float*)d_in[5];
    const float* tlb   = (const float*)d_in[6];
    const float* trW   = (const float*)d_in[7];
    const float* trU   = (const float*)d_in[8];
    const float* trb   = (const float*)d_in[9];
    const float* wih0L = (const float*)d_in[10];
    const float* b0L   = (const float*)d_in[12];
    const float* b1L   = (const float*)d_in[15];
    const float* wih0R = (const float*)d_in[16];
    const float* b0R   = (const float*)d_in[18];
    const float* b1R   = (const float*)d_in[21];
    const float* mW1   = (const float*)d_in[22];
    const float* mb1   = (const float*)d_in[23];
    const float* mW2   = (const float*)d_in[24];
    const float* mb2   = (const float*)d_in[25];

    // workspace layout (bytes)
    char* ws = (char*)d_ws;
    f16*   w16    = (f16*)ws;                        // 6 x 262144 f16 = 3 MB
    float* states = (float*)(ws + 3145728);          // 2x256x128 f32 = 256 KB
    float* h1out  = (float*)(ws + 3407872);          // 2x256x256 f32 = 512 KB
    f16*   h0img  = (f16*)(ws + 3932160);            // 2x16x128x4096 f16 = 32 MB

    f16* whh0 = w16;                 // [2][1024][256]
    f16* whh1 = w16 + 2 * 262144;
    f16* wih1 = w16 + 4 * 262144;

    P6 p { (const float*)d_in[11], (const float*)d_in[17],   // nl_Whh0, nr_Whh0
           (const float*)d_in[14], (const float*)d_in[20],   // nl_Whh1, nr_Whh1
           (const float*)d_in[13], (const float*)d_in[19] }; // nl_Wih1, nr_Wih1
    k_cvt<<<6144, 256, 0, stream>>>(p, w16);
    k_scalar_lstm<<<512, 128, 0, stream>>>(ln, rn, tlW, tlU, tlb, trW, trU, trb, states);
    k_rec<0><<<32, 1024, 0, stream>>>(states, whh0, nullptr, nullptr, h0img,
                                      wih0L, wih0R, b0L, b0R, nullptr);
    k_rec<1><<<32, 1024, 0, stream>>>(nullptr, whh1, wih1, h0img, nullptr,
                                      nullptr, nullptr, b1L, b1R, h1out);
    k_mlp<<<256, 256, 0, stream>>>(h1out, mW1, mb1, mW2, mb2, (float*)d_out);
}